// Round 5
// baseline (59.432 us; speedup 1.0000x reference)
//
#include <hip/hip_runtime.h>
#include <hip/hip_bf16.h>
#include <math.h>

#define LA 1536
#define LS 512
#define LT 2048
#define CC 256
#define NH 4
#define DKH 64
#define NB 4
#define NT (LT / 64)
#define NTA (LA / 64)     // 24 audio tiles
#define NSPLIT 4
#define SZ ((size_t)NB * LT * CC)   // 2M elements

// Q pre-scale: (1/sqrt(64)) * log2(e)  -> softmax runs in exp2 domain
#define QSCALE 0.1803368801111244f

typedef _Float16 f16;
typedef __attribute__((ext_vector_type(8))) _Float16 f16x8;
typedef __attribute__((ext_vector_type(4))) _Float16 f16x4;
typedef __attribute__((ext_vector_type(4))) float f32x4;

__device__ inline f16x8 cvt8(const float4 a, const float4 b) {
    f16x8 h;
    h[0] = (_Float16)a.x; h[1] = (_Float16)a.y; h[2] = (_Float16)a.z; h[3] = (_Float16)a.w;
    h[4] = (_Float16)b.x; h[5] = (_Float16)b.y; h[6] = (_Float16)b.z; h[7] = (_Float16)b.w;
    return h;
}

// ---------------------------------------------------------------------------
// Kernel 1: fused QKV projection, fp16 MFMA, 128x128 tiles (was 128x64:
// halves x re-fetch, doubles MFMA per staged byte).
// Q gets QSCALE folded in (exp2-domain softmax). V written transposed
// Vt[(b*NH+h)*DKH+d][l] via LDS transpose (two 64-col passes).
// ---------------------------------------------------------------------------
__global__ __launch_bounds__(256) void qkv_mfma(
    const float* __restrict__ audio, const float* __restrict__ text,
    const float* __restrict__ Wq, const float* __restrict__ bq,
    const float* __restrict__ Wk, const float* __restrict__ bk,
    const float* __restrict__ Wv, const float* __restrict__ bv,
    f16* __restrict__ Qh, f16* __restrict__ Kh, f16* __restrict__ Vth)
{
    __shared__ f16 smem[128 * 64 + 128 * 64];   // As | Bs ; Ts reuses front
    f16* As = smem;              // [m 0..127][k-chunk swizzled]
    f16* Bs = smem + 128 * 64;   // [n 0..127][k-chunk swizzled]

    const int tid = threadIdx.x;
    const int w = tid >> 6, l = tid & 63;
    const int g = l >> 4, r = l & 15;

    const int m0 = blockIdx.x * 128;
    const int n0g = blockIdx.y * 128;   // 0..640
    const int mat = n0g >> 8;           // 0=Q 1=K 2=V
    const int ch0 = n0g & 255;          // 0 or 128

    const float* W    = (mat == 0) ? Wq : (mat == 1) ? Wk : Wv;
    const float* bias = (mat == 0) ? bq : (mat == 1) ? bk : bv;

    const int b  = m0 >> 11;
    const int l0 = m0 & 2047;           // 1536 % 128 == 0 -> clean split

    f32x4 acc[2][8] = {};

    for (int k0 = 0; k0 < CC; k0 += 64) {
        #pragma unroll
        for (int mm = 0; mm < 4; ++mm) {           // A: 128 rows x 8 chunks
            const int idx = mm * 256 + tid;
            const int row = idx >> 3, c = idx & 7;
            const int lrow = l0 + row;
            const float* src = (lrow < LA)
                ? (audio + ((size_t)b * LA + lrow) * CC + k0 + c * 8)
                : (text  + ((size_t)b * LS + (lrow - LA)) * CC + k0 + c * 8);
            const float4 x0 = *(const float4*)src;
            const float4 x1 = *(const float4*)(src + 4);
            *(f16x8*)(As + row * 64 + ((c ^ (row & 7)) << 3)) = cvt8(x0, x1);
        }
        #pragma unroll
        for (int mm = 0; mm < 4; ++mm) {           // B: 128 rows x 8 chunks
            const int idx = mm * 256 + tid;
            const int row = idx >> 3, c = idx & 7;
            const float* src = W + (size_t)(ch0 + row) * CC + k0 + c * 8;
            const float4 x0 = *(const float4*)src;
            const float4 x1 = *(const float4*)(src + 4);
            *(f16x8*)(Bs + row * 64 + ((c ^ (row & 7)) << 3)) = cvt8(x0, x1);
        }
        __syncthreads();
        #pragma unroll
        for (int kc = 0; kc < 2; ++kc) {
            f16x8 af[2];
            #pragma unroll
            for (int i = 0; i < 2; ++i) {
                const int row = w * 32 + i * 16 + r;
                const int c = kc * 4 + g;
                af[i] = *(const f16x8*)(As + row * 64 + ((c ^ (row & 7)) << 3));
            }
            #pragma unroll
            for (int jh = 0; jh < 2; ++jh) {
                f16x8 bf[4];
                #pragma unroll
                for (int j = 0; j < 4; ++j) {
                    const int row = (jh * 4 + j) * 16 + r;
                    const int c = kc * 4 + g;
                    bf[j] = *(const f16x8*)(Bs + row * 64 + ((c ^ (row & 7)) << 3));
                }
                #pragma unroll
                for (int i = 0; i < 2; ++i)
                    #pragma unroll
                    for (int j = 0; j < 4; ++j)
                        acc[i][jh * 4 + j] = __builtin_amdgcn_mfma_f32_16x16x32_f16(
                            af[i], bf[j], acc[i][jh * 4 + j], 0, 0, 0);
            }
        }
        __syncthreads();
    }

    float bcol[8];
    #pragma unroll
    for (int j = 0; j < 8; ++j) bcol[j] = bias[ch0 + j * 16 + r];

    if (mat <= 1) {
        f16* Out = (mat == 0) ? Qh : Kh;
        const float osc = (mat == 0) ? QSCALE : 1.0f;
        #pragma unroll
        for (int i = 0; i < 2; ++i)
            #pragma unroll
            for (int e = 0; e < 4; ++e) {
                const int m = m0 + w * 32 + i * 16 + g * 4 + e;
                #pragma unroll
                for (int j = 0; j < 8; ++j)
                    Out[(size_t)m * CC + ch0 + j * 16 + r] =
                        (_Float16)((acc[i][j][e] + bcol[j]) * osc);
            }
    } else {
        // V: two 64-col transpose passes through Ts[64][136]
        f16* Ts = smem;
        const int b2 = m0 >> 11, l0m = m0 & 2047;
        #pragma unroll
        for (int pass = 0; pass < 2; ++pass) {
            #pragma unroll
            for (int i = 0; i < 2; ++i)
                #pragma unroll
                for (int e = 0; e < 4; ++e) {
                    const int ml = w * 32 + i * 16 + g * 4 + e;
                    #pragma unroll
                    for (int j = 0; j < 4; ++j)
                        Ts[(j * 16 + r) * 136 + ml] =
                            (_Float16)(acc[i][pass * 4 + j][e] + bcol[pass * 4 + j]);
                }
            __syncthreads();
            #pragma unroll
            for (int u = 0; u < 4; ++u) {
                const int idx = u * 256 + tid;
                const int nl = idx >> 4, mc = idx & 15;
                const f16x8 vv = *(const f16x8*)(Ts + nl * 136 + mc * 8);
                const int nglob = ch0 + pass * 64 + nl;
                const int hh = nglob >> 6, dd = nglob & 63;
                *(f16x8*)(Vth + ((size_t)((b2 * NH + hh) * DKH + dd)) * LT + l0m + mc * 8) = vv;
            }
            __syncthreads();
        }
    }
}

// ---------------------------------------------------------------------------
// Kernel 2: flash attention, GRID-LEVEL SPLIT-K x4 (fills the device:
// 2048 blocks x 4 waves -> ~24 waves/CU vs 8-16 before).
// Split sp handles live tiles p = sp, sp+4, ... Partials: normalized-f16 o
// + (m,l) f32, combined by attn_combine. exp2-domain softmax (QSCALE folded),
// defer-rescale via __all(m_new==m_run).
// ---------------------------------------------------------------------------
__global__ __launch_bounds__(256) void attn_f16(
    const f16* __restrict__ Q, const f16* __restrict__ K,
    const f16* __restrict__ Vt,
    const int* __restrict__ slen, const int* __restrict__ tlen,
    f16* __restrict__ Po, float2* __restrict__ Ml)
{
    __shared__ f16 Ks[4096];          // [key][d], swizzled
    __shared__ f16 Vts[4096];         // [d][key], swizzled
    __shared__ f16 Ps[4][16 * 72];    // per-wave P

    const int tid = threadIdx.x;
    const int w = tid >> 6, l = tid & 63;
    const int g = l >> 4, r = l & 15;

    const int q0 = blockIdx.x * 64;
    const int h  = blockIdx.y;
    const int b  = blockIdx.z >> 2;
    const int sp = blockIdx.z & 3;

    const int ilen = slen[b];
    const int kcap = LA + tlen[b];
    const int nskip = ilen >> 6;
    int ntskip = 0;
    if (q0 >= LA) {
        const int skipmax = min(q0 - 63, kcap - 64);
        const int d = skipmax - LA;
        ntskip = (d < 0) ? 0 : ((d >> 6) + 1);
    }
    const int nAudio = NTA - nskip;                  // >= 1
    const int nProc  = nAudio + (NT - NTA) - ntskip;
    const int nIter  = (nProc > sp) ? ((nProc - sp + NSPLIT - 1) >> 2) : 0;

    const int qrow = q0 + 16 * w + r;

    // Q fragment (QSCALE already folded in by qkv_mfma)
    f16x8 qf[2];
    #pragma unroll
    for (int ch = 0; ch < 2; ++ch)
        qf[ch] = *(const f16x8*)(Q + ((size_t)(b * LT) + qrow) * CC + h * DKH + ch * 32 + g * 8);

    const int srow0 = tid >> 3, scc = tid & 7;
    const int srow1 = srow0 + 32;
    const int sdst0 = srow0 * 64 + ((scc ^ (srow0 & 7)) << 3);
    const int sdst1 = srow1 * 64 + ((scc ^ (srow1 & 7)) << 3);

    #define TILE_OF(p) ((p) < nAudio ? (nskip + (p)) : (NTA + ntskip + ((p) - nAudio)))

    if (nIter > 0) {        // prologue: stage first tile
        const int k0 = TILE_OF(sp) * 64;
        *(f16x8*)(Ks + sdst0)  = *(const f16x8*)(K  + ((size_t)(b * LT) + k0 + srow0) * CC + h * DKH + scc * 8);
        *(f16x8*)(Vts + sdst0) = *(const f16x8*)(Vt + ((size_t)((b * NH + h) * DKH) + srow0) * LT + k0 + scc * 8);
        *(f16x8*)(Ks + sdst1)  = *(const f16x8*)(K  + ((size_t)(b * LT) + k0 + srow1) * CC + h * DKH + scc * 8);
        *(f16x8*)(Vts + sdst1) = *(const f16x8*)(Vt + ((size_t)((b * NH + h) * DKH) + srow1) * LT + k0 + scc * 8);
    }
    __syncthreads();

    float m_run = -1e30f, l_run = 0.0f;
    f32x4 o[4] = {};   // o[dsb][e]: O[q=4g+e][d=16*dsb+r]

    for (int i = 0; i < nIter; ++i) {
        const int pcur = sp + NSPLIT * i;
        const int kt = TILE_OF(pcur);
        const int k0 = kt * 64;
        const bool nxtV = (pcur + NSPLIT) < nProc;

        f16x8 kr0, vr0, kr1, vr1;
        if (nxtV) {
            const int kn = TILE_OF(pcur + NSPLIT) * 64;
            kr0 = *(const f16x8*)(K  + ((size_t)(b * LT) + kn + srow0) * CC + h * DKH + scc * 8);
            vr0 = *(const f16x8*)(Vt + ((size_t)((b * NH + h) * DKH) + srow0) * LT + kn + scc * 8);
            kr1 = *(const f16x8*)(K  + ((size_t)(b * LT) + kn + srow1) * CC + h * DKH + scc * 8);
            vr1 = *(const f16x8*)(Vt + ((size_t)((b * NH + h) * DKH) + srow1) * LT + kn + scc * 8);
        }

        // ---- S^T = K . Q^T (exp2 domain)
        f32x4 sacc[4] = {};
        #pragma unroll
        for (int s = 0; s < 4; ++s) {
            const int row = 16 * s + r;
            #pragma unroll
            for (int ch = 0; ch < 2; ++ch) {
                const f16x8 a = *(const f16x8*)(Ks + row * 64 + ((((ch * 4 + g) ^ (row & 7)) & 7) << 3));
                sacc[s] = __builtin_amdgcn_mfma_f32_16x16x32_f16(a, qf[ch], sacc[s], 0, 0, 0);
            }
        }

        // ---- mask (block-uniform mode)
        const int mode = (kt < NTA) ? ((k0 >= ilen) ? 0 : 1)
                                    : ((q0 < LA) ? 0 : 2);
        float sv[16];
        if (mode == 0) {
            #pragma unroll
            for (int s = 0; s < 4; ++s)
                #pragma unroll
                for (int e = 0; e < 4; ++e) sv[s * 4 + e] = sacc[s][e];
        } else if (mode == 1) {
            #pragma unroll
            for (int s = 0; s < 4; ++s)
                #pragma unroll
                for (int e = 0; e < 4; ++e) {
                    const int kk = k0 + 16 * s + 4 * g + e;
                    sv[s * 4 + e] = (kk >= ilen) ? sacc[s][e] : -INFINITY;
                }
        } else {
            #pragma unroll
            for (int s = 0; s < 4; ++s)
                #pragma unroll
                for (int e = 0; e < 4; ++e) {
                    const int kk = k0 + 16 * s + 4 * g + e;
                    sv[s * 4 + e] = (kk > qrow || kk >= kcap) ? sacc[s][e] : -INFINITY;
                }
        }

        // ---- online softmax, exp2 domain, finite sentinel
        float mloc = -1e30f;
        #pragma unroll
        for (int u = 0; u < 16; ++u) mloc = fmaxf(mloc, sv[u]);
        mloc = fmaxf(mloc, __shfl_xor(mloc, 16));
        mloc = fmaxf(mloc, __shfl_xor(mloc, 32));
        const float m_new = fmaxf(m_run, mloc);

        float ssum = 0.0f;
        f16x4 ph[4];
        #pragma unroll
        for (int s = 0; s < 4; ++s)
            #pragma unroll
            for (int e = 0; e < 4; ++e) {
                const float p = exp2f(sv[s * 4 + e] - m_new);   // exp2(-inf)=0
                ph[s][e] = (_Float16)p;
                ssum += p;
            }
        ssum += __shfl_xor(ssum, 16);
        ssum += __shfl_xor(ssum, 32);

        if (__all(m_new == m_run)) {           // defer-rescale (common case)
            l_run += ssum;
        } else {
            const float sc = exp2f(m_run - m_new);
            l_run = l_run * sc + ssum;
            m_run = m_new;
            #pragma unroll
            for (int e = 0; e < 4; ++e) {
                const float scr = __shfl(sc, 4 * g + e);
                #pragma unroll
                for (int dsb = 0; dsb < 4; ++dsb) o[dsb][e] *= scr;
            }
        }

        // ---- P -> per-wave LDS re-layout
        #pragma unroll
        for (int s = 0; s < 4; ++s)
            *(f16x4*)(&Ps[w][0] + r * 72 + 16 * s + 4 * g) = ph[s];

        // ---- O += P . V
        #pragma unroll
        for (int ch = 0; ch < 2; ++ch) {
            const f16x8 a = *(const f16x8*)(&Ps[w][0] + r * 72 + ch * 32 + g * 8);
            #pragma unroll
            for (int dsb = 0; dsb < 4; ++dsb) {
                const int vrow = 16 * dsb + r;
                const f16x8 bf = *(const f16x8*)(Vts + vrow * 64 + ((((ch * 4 + g) ^ (vrow & 7)) & 7) << 3));
                o[dsb] = __builtin_amdgcn_mfma_f32_16x16x32_f16(a, bf, o[dsb], 0, 0, 0);
            }
        }

        __syncthreads();                       // LDS reads done
        if (nxtV) {
            *(f16x8*)(Ks + sdst0)  = kr0;
            *(f16x8*)(Vts + sdst0) = vr0;
            *(f16x8*)(Ks + sdst1)  = kr1;
            *(f16x8*)(Vts + sdst1) = vr1;
        }
        __syncthreads();                       // writes visible
    }

    // ---- epilogue: normalized partial + (m,l)
    const float linv = (l_run > 0.0f) ? 1.0f / l_run : 0.0f;
    #pragma unroll
    for (int e = 0; e < 4; ++e) {
        const float inv = __shfl(linv, 4 * g + e);
        const int qq = q0 + 16 * w + 4 * g + e;
        #pragma unroll
        for (int dsb = 0; dsb < 4; ++dsb)
            Po[(size_t)sp * SZ + ((size_t)(b * LT) + qq) * CC + h * DKH + 16 * dsb + r] =
                (_Float16)(o[dsb][e] * inv);
    }
    if (g == 0)
        Ml[((size_t)(sp * NB + b) * NH + h) * LT + q0 + 16 * w + r] =
            make_float2(m_run, l_run);
    #undef TILE_OF
}

// ---------------------------------------------------------------------------
// Kernel 2b: combine split-K partials.  AO = sum_s w_s * o_s / sum_s w_s,
// w_s = l_s * 2^(m_s - m*).
// ---------------------------------------------------------------------------
__global__ __launch_bounds__(256) void attn_combine(
    const f16* __restrict__ Po, const float2* __restrict__ Ml,
    f16* __restrict__ AOh)
{
    const int idx = blockIdx.x * 256 + threadIdx.x;
    const size_t flat = (size_t)idx * 8;
    const int qg = (int)(flat >> 8);       // b*LT + q
    const int c  = (int)(flat & 255);
    const int b  = qg >> 11, q = qg & 2047;
    const int h  = c >> 6;

    float m_i[NSPLIT], l_i[NSPLIT];
    float mt = -1e30f;
    #pragma unroll
    for (int s = 0; s < NSPLIT; ++s) {
        const float2 ml = Ml[((size_t)(s * NB + b) * NH + h) * LT + q];
        m_i[s] = ml.x; l_i[s] = ml.y;
        mt = fmaxf(mt, m_i[s]);
    }
    float wgt[NSPLIT], denom = 0.0f;
    #pragma unroll
    for (int s = 0; s < NSPLIT; ++s) {
        wgt[s] = l_i[s] * exp2f(m_i[s] - mt);
        denom += wgt[s];
    }
    const float inv = 1.0f / denom;

    float a8[8] = {};
    #pragma unroll
    for (int s = 0; s < NSPLIT; ++s) {
        const f16x8 o8 = *(const f16x8*)(Po + (size_t)s * SZ + flat);
        #pragma unroll
        for (int e = 0; e < 8; ++e) a8[e] += wgt[s] * (float)o8[e];
    }
    f16x8 r8;
    #pragma unroll
    for (int e = 0; e < 8; ++e) r8[e] = (_Float16)(a8[e] * inv);
    *(f16x8*)(AOh + flat) = r8;
}

// ---------------------------------------------------------------------------
// Kernel 3: output projection, fp16 MFMA, 128x128 tiles, fp32 out.
// ---------------------------------------------------------------------------
__global__ __launch_bounds__(256) void out_mfma(
    const f16* __restrict__ X, const float* __restrict__ Wo,
    const float* __restrict__ bo, float* __restrict__ Out)
{
    __shared__ f16 As[128 * 64];
    __shared__ f16 Bs[128 * 64];

    const int tid = threadIdx.x;
    const int w = tid >> 6, l = tid & 63;
    const int g = l >> 4, r = l & 15;

    const int m0 = blockIdx.x * 128;
    const int n0 = blockIdx.y * 128;

    f32x4 acc[2][8] = {};

    for (int k0 = 0; k0 < CC; k0 += 64) {
        #pragma unroll
        for (int mm = 0; mm < 4; ++mm) {
            const int idx = mm * 256 + tid;
            const int row = idx >> 3, c = idx & 7;
            *(f16x8*)(As + row * 64 + ((c ^ (row & 7)) << 3)) =
                *(const f16x8*)(X + (size_t)(m0 + row) * CC + k0 + c * 8);
        }
        #pragma unroll
        for (int mm = 0; mm < 4; ++mm) {
            const int idx = mm * 256 + tid;
            const int row = idx >> 3, c = idx & 7;
            const float* src = Wo + (size_t)(n0 + row) * CC + k0 + c * 8;
            const float4 x0 = *(const float4*)src;
            const float4 x1 = *(const float4*)(src + 4);
            *(f16x8*)(Bs + row * 64 + ((c ^ (row & 7)) << 3)) = cvt8(x0, x1);
        }
        __syncthreads();
        #pragma unroll
        for (int kc = 0; kc < 2; ++kc) {
            f16x8 af[2];
            #pragma unroll
            for (int i = 0; i < 2; ++i) {
                const int row = w * 32 + i * 16 + r;
                const int c = kc * 4 + g;
                af[i] = *(const f16x8*)(As + row * 64 + ((c ^ (row & 7)) << 3));
            }
            #pragma unroll
            for (int jh = 0; jh < 2; ++jh) {
                f16x8 bf[4];
                #pragma unroll
                for (int j = 0; j < 4; ++j) {
                    const int row = (jh * 4 + j) * 16 + r;
                    const int c = kc * 4 + g;
                    bf[j] = *(const f16x8*)(Bs + row * 64 + ((c ^ (row & 7)) << 3));
                }
                #pragma unroll
                for (int i = 0; i < 2; ++i)
                    #pragma unroll
                    for (int j = 0; j < 4; ++j)
                        acc[i][jh * 4 + j] = __builtin_amdgcn_mfma_f32_16x16x32_f16(
                            af[i], bf[j], acc[i][jh * 4 + j], 0, 0, 0);
            }
        }
        __syncthreads();
    }

    float bcol[8];
    #pragma unroll
    for (int j = 0; j < 8; ++j) bcol[j] = bo[n0 + j * 16 + r];

    #pragma unroll
    for (int i = 0; i < 2; ++i)
        #pragma unroll
        for (int e = 0; e < 4; ++e) {
            const int m = m0 + w * 32 + i * 16 + g * 4 + e;
            #pragma unroll
            for (int j = 0; j < 8; ++j)
                Out[(size_t)m * CC + n0 + j * 16 + r] = acc[i][j][e] + bcol[j];
        }
}

// ---------------------------------------------------------------------------
extern "C" void kernel_launch(void* const* d_in, const int* in_sizes, int n_in,
                              void* d_out, int out_size, void* d_ws, size_t ws_size,
                              hipStream_t stream)
{
    const float* audio = (const float*)d_in[0];
    const float* text  = (const float*)d_in[1];
    const int*   slen  = (const int*)d_in[2];
    const int*   tlen  = (const int*)d_in[3];
    const float* Wq = (const float*)d_in[4];
    const float* bq = (const float*)d_in[5];
    const float* Wk = (const float*)d_in[6];
    const float* bk = (const float*)d_in[7];
    const float* Wv = (const float*)d_in[8];
    const float* bv = (const float*)d_in[9];
    const float* Wo = (const float*)d_in[10];
    const float* bo = (const float*)d_in[11];
    float* out = (float*)d_out;

    // ws: Qh,Kh,Vth,AOh (SZ f16 each) | Po (NSPLIT*SZ f16) | Ml (float2)
    f16* Qh  = (f16*)d_ws;
    f16* Kh  = Qh + SZ;
    f16* Vth = Kh + SZ;
    f16* AOh = Vth + SZ;
    f16* Po  = AOh + SZ;
    float2* Ml = (float2*)(Po + (size_t)NSPLIT * SZ);

    qkv_mfma<<<dim3(64, 6), 256, 0, stream>>>(audio, text, Wq, bq, Wk, bk, Wv, bv,
                                              Qh, Kh, Vth);
    attn_f16<<<dim3(LT / 64, NH, NB * NSPLIT), 256, 0, stream>>>(Qh, Kh, Vth,
                                                                 slen, tlen, Po, Ml);
    attn_combine<<<dim3((NB * LT * CC / 8) / 256), 256, 0, stream>>>(Po, Ml, AOh);
    out_mfma<<<dim3(64, 2), 256, 0, stream>>>(AOh, Wo, bo, out);
}